// Round 3
// baseline (36.117 us; speedup 1.0000x reference)
//
#include <hip/hip_runtime.h>

// Problem constants (match the reference)
#define T_DIM 160
#define B_DIM 64
#define C_DIM 6625
#define S_DIM 25
#define L_DIM 51            // 2*S+1
#define J_DIM 26            // distinct class slots: blank + 25 labels
#define NEGV  (-1.0e30f)
#define LOG2E 1.4426950408889634f
#define LN2   0.6931471805599453f
#define GCHUNK  16
#define NGCHUNK (T_DIM / GCHUNK)   // 10

// ---------------------------------------------------------------------------
// Kernel 1: wide gather. Block (b, c) fetches the 26 needed classes for
// t in [16c, 16c+16), prescales by log2(e), writes emit_ws[b][t][26].
// 640 blocks spread the scattered-line fetch across all CUs.
// ---------------------------------------------------------------------------
__global__ __launch_bounds__(256)
void ctc_gather(const float* __restrict__ preds,     // [T,B,C]
                const int*   __restrict__ targets,   // [B,S]
                float*       __restrict__ emit_ws)   // [B,T,26]
{
    const int b   = blockIdx.x;
    const int c   = blockIdx.y;
    const int tid = threadIdx.x;

    __shared__ int cls_s[J_DIM];
    if (tid < J_DIM) cls_s[tid] = (tid == 0) ? 0 : targets[b * S_DIM + tid - 1];
    __syncthreads();

    const int t0 = c * GCHUNK;
    for (int flat = tid; flat < GCHUNK * J_DIM; flat += 256) {
        int tl = flat / J_DIM;
        int j  = flat - tl * J_DIM;
        int t  = t0 + tl;
        float v = preds[((size_t)t * B_DIM + b) * C_DIM + cls_s[j]];
        emit_ws[((size_t)b * T_DIM + t) * J_DIM + j] = v * LOG2E;
    }
}

// ---------------------------------------------------------------------------
// Kernel 2: recurrence. One block per batch element; all 256 threads burst
// the contiguous 16.6 KB emission slab into LDS, then wave 0 runs the
// 159-step alpha chain (lane l = lattice position, log2 domain).
// ---------------------------------------------------------------------------
__global__ __launch_bounds__(256)
void ctc_alpha(const float* __restrict__ emit_ws,    // [B,T,26]
               const int*   __restrict__ targets,    // [B,S]
               const int*   __restrict__ tlen,       // [B]
               float*       __restrict__ out)        // scalar (pre-zeroed)
{
    const int b   = blockIdx.x;
    const int tid = threadIdx.x;

    __shared__ float emit_s[T_DIM * J_DIM];          // 4160 f32 = 16.6 KB

    // Contiguous burst load: 1040 float4s over 256 threads.
    {
        const float4* src = (const float4*)(emit_ws + (size_t)b * T_DIM * J_DIM);
        float4*       dst = (float4*)emit_s;
        #pragma unroll
        for (int i = tid; i < (T_DIM * J_DIM) / 4; i += 256) dst[i] = src[i];
    }
    __syncthreads();
    if (tid >= 64) return;                            // recurrence on wave 0 only

    const int  l      = tid;                          // lattice position
    const bool active = (l < L_DIM);
    const int  j      = active ? ((l & 1) ? (l >> 1) + 1 : 0) : 0;
    const int  addr1  = ((l >= 1) ? l - 1 : l) << 2;  // ds_bpermute byte addrs
    const int  addr2  = ((l >= 2) ? l - 2 : l) << 2;

    bool skipf = false;
    if (active && (l & 1) && l >= 3) {
        int i = l >> 1;
        skipf = (targets[b * S_DIM + i] != targets[b * S_DIM + i - 1]);
    }

    float alpha = NEGV;                               // log2-domain alpha
    if (l == 0) alpha = emit_s[0];                    // t=0, blank slot
    if (l == 1) alpha = emit_s[1];                    // t=0, label 0 slot

    float e_next = emit_s[1 * J_DIM + j];             // prefetch t=1
    for (int t = 1; t < T_DIM; ++t) {
        float e = e_next;
        if (t + 1 < T_DIM) e_next = emit_s[(t + 1) * J_DIM + j];  // off-chain
        float a1 = alpha;
        float a2 = __int_as_float(
            __builtin_amdgcn_ds_bpermute(addr1, __float_as_int(alpha)));
        float a3 = __int_as_float(
            __builtin_amdgcn_ds_bpermute(addr2, __float_as_int(alpha)));
        if (l < 1)  a2 = NEGV;
        if (!skipf) a3 = NEGV;
        float m = fmaxf(fmaxf(a1, a2), a3);           // v_max3
        float s = exp2f(a1 - m) + exp2f(a2 - m) + exp2f(a3 - m);
        alpha = m + log2f(s) + (active ? e : 0.0f);
    }

    // nll = -ln2 * log2addexp2(alpha[2*len], alpha[2*len-1])
    const int len = tlen[b];
    const int idx = 2 * len;                          // in [10, 50]
    float l_last = __shfl(alpha, idx, 64);
    float l_prev = __shfl(alpha, idx - 1, 64);
    if (tid == 0) {
        float m   = fmaxf(l_last, l_prev);
        float r2  = m + log2f(exp2f(l_last - m) + exp2f(l_prev - m));
        float nll = -r2 * LN2;
        float per = (nll >= 1e29f) ? 0.0f : nll / (float)len;
        atomicAdd(out, per * (1.0f / B_DIM));
    }
}

// ---------------------------------------------------------------------------
// Fallback (R2 fused kernel) if ws_size can't hold the emission workspace.
// ---------------------------------------------------------------------------
#define CHUNK  16
#define NCHUNK (T_DIM / CHUNK)
__global__ __launch_bounds__(256)
void ctc_alpha_fused(const float* __restrict__ preds,
                     const int*   __restrict__ targets,
                     const int*   __restrict__ tlen,
                     float*       __restrict__ out)
{
    const int b   = blockIdx.x;
    const int tid = threadIdx.x;
    __shared__ float emit_s[T_DIM * L_DIM];
    __shared__ int   ext_s[L_DIM];
    if (tid < L_DIM) {
        int cls = (tid & 1) ? targets[b * S_DIM + (tid >> 1)] : 0;
        ext_s[tid] = cls;
    }
    __syncthreads();
    const size_t row_stride = (size_t)B_DIM * C_DIM;
    const float* pb = preds + (size_t)b * C_DIM;
    for (int flat = tid; flat < CHUNK * L_DIM; flat += 256) {
        int t = flat / L_DIM;
        int l = flat - t * L_DIM;
        emit_s[flat] = pb[(size_t)t * row_stride + ext_s[l]] * LOG2E;
    }
    __syncthreads();
    const int l = tid;
    const int l_eff = (l < L_DIM) ? l : (L_DIM - 1);
    const int addr1 = ((l >= 1) ? l - 1 : 0) << 2;
    const int addr2 = ((l >= 2) ? l - 2 : 0) << 2;
    bool skipf = false;
    if (tid < 64 && (l & 1) && l >= 3 && l < L_DIM) {
        int i = l >> 1;
        skipf = (targets[b * S_DIM + i] != targets[b * S_DIM + i - 1]);
    }
    float alpha = NEGV;
    if (tid == 0) alpha = emit_s[0];
    if (tid == 1) alpha = emit_s[1];
    int t = 1;
    for (int c = 0; c < NCHUNK; ++c) {
        if (tid >= 64) {
            if (c + 1 < NCHUNK) {
                const int base = (c + 1) * CHUNK * L_DIM;
                const int t0   = (c + 1) * CHUNK;
                for (int flat = tid - 64; flat < CHUNK * L_DIM; flat += 192) {
                    int tt = flat / L_DIM;
                    int ll = flat - tt * L_DIM;
                    emit_s[base + flat] =
                        pb[(size_t)(t0 + tt) * row_stride + ext_s[ll]] * LOG2E;
                }
            }
        } else {
            const int tend = (c + 1) * CHUNK;
            for (; t < tend; ++t) {
                float a1 = alpha;
                float a2 = __int_as_float(
                    __builtin_amdgcn_ds_bpermute(addr1, __float_as_int(alpha)));
                float a3 = __int_as_float(
                    __builtin_amdgcn_ds_bpermute(addr2, __float_as_int(alpha)));
                if (l < 1)  a2 = NEGV;
                if (!skipf) a3 = NEGV;
                float m = fmaxf(fmaxf(a1, a2), a3);
                float s = exp2f(a1 - m) + exp2f(a2 - m) + exp2f(a3 - m);
                alpha = m + log2f(s) + emit_s[t * L_DIM + l_eff];
            }
        }
        __syncthreads();
    }
    if (tid < 64) {
        const int len = tlen[b];
        const int idx = 2 * len;
        float l_last = __shfl(alpha, idx, 64);
        float l_prev = __shfl(alpha, idx - 1, 64);
        if (tid == 0) {
            float m   = fmaxf(l_last, l_prev);
            float r2  = m + log2f(exp2f(l_last - m) + exp2f(l_prev - m));
            float nll = -r2 * LN2;
            float per = (nll >= 1e29f) ? 0.0f : nll / (float)len;
            atomicAdd(out, per * (1.0f / B_DIM));
        }
    }
}

extern "C" void kernel_launch(void* const* d_in, const int* in_sizes, int n_in,
                              void* d_out, int out_size, void* d_ws, size_t ws_size,
                              hipStream_t stream)
{
    const float* preds   = (const float*)d_in[0];   // [T,B,C] fp32
    const int*   targets = (const int*)d_in[1];     // [B,S]
    const int*   tlen    = (const int*)d_in[2];     // [B]
    float* out = (float*)d_out;                     // scalar

    hipMemsetAsync(out, 0, sizeof(float), stream);  // out accumulates atomically

    const size_t ws_needed = (size_t)B_DIM * T_DIM * J_DIM * sizeof(float);
    if (ws_size >= ws_needed) {
        float* emit_ws = (float*)d_ws;
        dim3 ggrid(B_DIM, NGCHUNK);
        ctc_gather<<<ggrid, 256, 0, stream>>>(preds, targets, emit_ws);
        ctc_alpha<<<B_DIM, 256, 0, stream>>>(emit_ws, targets, tlen, out);
    } else {
        ctc_alpha_fused<<<B_DIM, 256, 0, stream>>>(preds, targets, tlen, out);
    }
}